// Round 1
// 1101.036 us; speedup vs baseline: 1.0830x; 1.0830x over previous
//
#include <hip/hip_runtime.h>

// TemporalAttentionDecoder_three_step: B=512, T=64, M=P=256. in f32, out f32.
// R8: 1192us. VALU 38%, HBM 0.4%, occ 21% -> L2-BW-bound on per-step weight
//     re-stream: 512 blk x 64 steps x 768KB (Wd+Whh f16) = 25GB L2 ~ 20TB/s.
// R9: 2 batch rows per block (grid 256, 512 thr), split-k across thread
//     halves: thread (kh,n) loads its weight H8 once, dots vs h/c of BOTH
//     rows -> each weight byte read once per block per step (L2 traffic /2).
//     Partial-k combine via LDS: x1 halves summed in B1 (x1a+x1b), gate
//     partials deferred to gates phase -> still 5 barriers/step.
//     LDS ~155KB -> 1 blk/CU, 8 waves/CU (same as R8's 2x4).
// f32 state: creg (register); f16: h,c,y1,E,ct,weights; dots accumulate f32.

typedef unsigned short u16;
typedef unsigned int u32;
typedef _Float16 half_t;
typedef half_t h2 __attribute__((ext_vector_type(2)));

#define BB 512
#define TT 64
#define MM 256
#define PP 256
#define YS 264   // y1l row stride (u16); measured conflict-free (R6/R7)
#define ES 68    // e16T row stride (u16); 2-way (free)
#define NROW 2
#define NTH 512

// ws layout (u16), all k-blocked n-major [kb][n][8]:
//   WdT8 [64kb][256n][8]  @ 0       (131072)
//   WhhT8[32kb][1024n][8] @ 131072  (262144)
//   WyT8 [64kb][256n][8]  @ 393216  (131072)
#define WD16_OFF  0
#define WHH16_OFF 131072
#define WY16_OFF  393216
#define WQ_ELEMS  524288
#define WQ_BYTES  (WQ_ELEMS * 2)

struct H8 { h2 p[4]; };   // 16B = 8 f16

#if defined(__has_builtin)
#if __has_builtin(__builtin_amdgcn_fdot2)
#define FDOT2(a, b, c) __builtin_amdgcn_fdot2((a), (b), (c), false)
#endif
#endif
#ifndef FDOT2
__device__ __forceinline__ float FDOT2(h2 a, h2 b, float c) {
  return c + (float)a[0] * (float)b[0] + (float)a[1] * (float)b[1];
}
#endif

__device__ __forceinline__ float dot8(const H8 w, const H8 a, float acc) {
  acc = FDOT2(w.p[0], a.p[0], acc);
  acc = FDOT2(w.p[1], a.p[1], acc);
  acc = FDOT2(w.p[2], a.p[2], acc);
  acc = FDOT2(w.p[3], a.p[3], acc);
  return acc;
}
__device__ __forceinline__ u16 f2h(float f) {
  union { half_t h; u16 u; } x; x.h = (half_t)f; return x.u;
}
__device__ __forceinline__ void unpackH8(const H8 v, float f[8]) {
#pragma unroll
  for (int i = 0; i < 8; ++i) f[i] = (float)v.p[i >> 1][i & 1];
}
__device__ __forceinline__ void ldf8(const float* p, float f[8]) {
  float4 a = *(const float4*)p;
  float4 b = *(const float4*)(p + 4);
  f[0]=a.x; f[1]=a.y; f[2]=a.z; f[3]=a.w;
  f[4]=b.x; f[5]=b.y; f[6]=b.z; f[7]=b.w;
}
__device__ __forceinline__ float tanh_fast(float x) {
  float e = __builtin_amdgcn_exp2f(x * 2.885390081777927f);
  return 1.0f - 2.0f * __builtin_amdgcn_rcpf(1.0f + e);
}
__device__ __forceinline__ float sigmoid_fast(float x) {
  float e = __builtin_amdgcn_exp2f(x * -1.4426950408889634f);
  return __builtin_amdgcn_rcpf(1.0f + e);
}

// ---- prep: f32 -> f16, k-blocked n-major ----
__global__ __launch_bounds__(256) void prep_kernel(
    const float* __restrict__ Wd, const float* __restrict__ Whh,
    const float* __restrict__ Wy, u16* __restrict__ o) {
  int i = blockIdx.x * 256 + threadIdx.x;   // 0..524287
  float v;
  if (i < WHH16_OFF) {
    int ki = i & 7, n = (i >> 3) & 255, kb = i >> 11;
    v = Wd[n * 512 + kb * 8 + ki];
  } else if (i < WY16_OFF) {
    int r = i - WHH16_OFF;
    int ki = r & 7, n = (r >> 3) & 1023, kb = r >> 13;
    v = Whh[n * 256 + kb * 8 + ki];
  } else {
    int r = i - WY16_OFF;
    int ki = r & 7, n = (r >> 3) & 255, kb = r >> 11;
    v = Wy[n * 512 + kb * 8 + ki];
  }
  o[i] = f2h(v);
}

template <int WQ>
__global__ __launch_bounds__(NTH, 2) void scan_kernel(
    const float* __restrict__ E,      // (B,T,M)
    const float* __restrict__ yin,    // (B,T,1)
    const float* __restrict__ tar,    // (B,2)
    const int*   __restrict__ train,  // (1)
    const void*  __restrict__ Wd_q,   // WQ1: WdT8 f16 | WQ0: f32 row-major
    const float* __restrict__ Wd_b,
    const float* __restrict__ Ud_w,   // (256,256) f32
    const float* __restrict__ vd_w,
    const float* __restrict__ wt_w,   // (257)
    const float* __restrict__ wt_b,
    const void*  __restrict__ Wy_q,
    const float* __restrict__ Wy_b,
    const float* __restrict__ vy_w,
    const float* __restrict__ vy_b,
    const float* __restrict__ Wih,    // (1024)
    const void*  __restrict__ Whh_q,
    const float* __restrict__ bih,
    const float* __restrict__ bhh,
    float* __restrict__ out)          // (3*B)
{
  __shared__ __align__(16) u16   y1l[NROW][TT * YS];   // 66KB f16 y1
  __shared__ __align__(16) u16   e16T[NROW][MM * ES];  // 68KB f16 E^T
  __shared__ __align__(16) u32   hs16[NROW][256];      // h pairs [0,128), c [128,256)
  __shared__ __align__(16) u32   ctx16p[NROW][128];    // ct f16 pairs
  __shared__ __align__(16) float ctx[NROW][MM];
  __shared__ __align__(16) float x1a[NROW][MM];        // kh=0 x1 partial (+bias)
  __shared__ __align__(16) float x1b[NROW][MM];        // kh=1 x1 partial
  __shared__ __align__(16) float lpart[NROW][4][TT];
  __shared__ __align__(16) u16   betas16[NROW][TT];
  __shared__ __align__(16) float part[10][MM];         // deferred gate partials
  __shared__ float red[8];
  __shared__ float sc[NROW];

  const int j  = threadIdx.x;          // 0..511
  const int n  = j & 255;              // output index
  const int kh = j >> 8;               // k-half (0/1) == staging row
  const int wv = j >> 6;               // wave 0..7
  const int b0 = blockIdx.x * NROW;    // batch rows b0, b0+1

  ((u32*)hs16)[j] = 0;
  float creg0 = 0.f, creg1 = 0.f;

  // gate constants (used by kh==0 threads)
  const float wih0 = Wih[n],       wih1 = Wih[n + 256];
  const float wih2 = Wih[n + 512], wih3 = Wih[n + 768];
  const float bb0 = bih[n]       + bhh[n];
  const float bb1 = bih[n + 256] + bhh[n + 256];
  const float bb2 = bih[n + 512] + bhh[n + 512];
  const float bb3 = bih[n + 768] + bhh[n + 768];
  const float wtM = wt_w[MM], wtb = wt_b[0];

  // ---- stage E^T (f16) into LDS for both rows ----
  {
    const float* __restrict__ Eb0 = E + (size_t)b0 * TT * MM;
    for (int i = j; i < NROW * TT * MM; i += NTH) {
      int r = i >> 14;
      int idx = i & 16383;
      int t = idx >> 8, m = idx & 255;
      e16T[r][m * ES + t] = f2h(Eb0[i]);
    }
  }

  // ---- y1 into LDS: thread computes column n of row kh for all 64 t ----
  {
    const float* __restrict__ Eb = E + (size_t)(b0 + kh) * TT * MM;
    const float* __restrict__ Uj = Ud_w + (size_t)n * MM;
    for (int t0 = 0; t0 < TT; t0 += 16) {
      float acc[16];
#pragma unroll
      for (int i = 0; i < 16; ++i) acc[i] = 0.f;
      for (int m0 = 0; m0 < MM; m0 += 8) {
        float w[8]; ldf8(Uj + m0, w);
#pragma unroll
        for (int tt = 0; tt < 16; ++tt) {
          float e[8]; ldf8(Eb + (size_t)(t0 + tt) * MM + m0, e);
#pragma unroll
          for (int mm = 0; mm < 8; ++mm) acc[tt] = fmaf(e[mm], w[mm], acc[tt]);
        }
      }
#pragma unroll
      for (int tt = 0; tt < 16; ++tt)
        y1l[kh][(t0 + tt) * YS + n] = f2h(acc[tt]);
    }
  }
  __syncthreads();

  // ---- gates: torch LSTMCell order i,f,g,o; writes h,c f16 (kh==0 only) ----
  auto gates_apply = [&](int r, float g0, float g1, float g2, float g3,
                         float ytil) {
    g0 += ytil * wih0 + bb0;
    g1 += ytil * wih1 + bb1;
    g2 += ytil * wih2 + bb2;
    g3 += ytil * wih3 + bb3;
    float& cr = r ? creg1 : creg0;
    float c = sigmoid_fast(g1) * cr + sigmoid_fast(g0) * tanh_fast(g2);
    float h = sigmoid_fast(g3) * tanh_fast(c);
    cr = c;
    u16* hsu = (u16*)hs16[r];
    hsu[n] = f2h(h);
    hsu[256 + n] = f2h(c);
  };

  // ---- head: ((concat[h,ct] @ Wy^T + b) . vy + b), split-k, both rows ----
  auto head_store = [&](int outIdx) {
    float p0 = 0.f, p1 = 0.f;
    if (WQ) {
      const u16* Wy16 = (const u16*)Wy_q;
      const u16* ph = Wy16 + (size_t)((kh * 16) * 256 + n) * 8;
      const u16* pc = Wy16 + (size_t)((32 + kh * 16) * 256 + n) * 8;
      const u32* hb0 = &hs16[0][kh * 64];
      const u32* hb1 = &hs16[1][kh * 64];
      const u32* cb0 = &ctx16p[0][kh * 64];
      const u32* cb1 = &ctx16p[1][kh * 64];
#pragma unroll 4
      for (int kb2 = 0; kb2 < 16; ++kb2) {
        H8 wh = *(const H8*)ph; ph += 2048;
        H8 wc = *(const H8*)pc; pc += 2048;
        H8 hp0 = *(const H8*)&hb0[kb2 * 4];
        H8 hp1 = *(const H8*)&hb1[kb2 * 4];
        H8 cp0 = *(const H8*)&cb0[kb2 * 4];
        H8 cp1 = *(const H8*)&cb1[kb2 * 4];
        p0 = dot8(wh, hp0, p0); p0 = dot8(wc, cp0, p0);
        p1 = dot8(wh, hp1, p1); p1 = dot8(wc, cp1, p1);
      }
    } else {
      const float* W = (const float*)Wy_q + (size_t)n * 512 + kh * 128;
#pragma unroll 2
      for (int kb2 = 0; kb2 < 16; ++kb2) {
        H8 hp0v = *(const H8*)&hs16[0][kh * 64 + kb2 * 4];
        H8 hp1v = *(const H8*)&hs16[1][kh * 64 + kb2 * 4];
        float hf0[8], hf1[8]; unpackH8(hp0v, hf0); unpackH8(hp1v, hf1);
        float ch0[8], ch1[8];
        ldf8(&ctx[0][kh * 128 + kb2 * 8], ch0);
        ldf8(&ctx[1][kh * 128 + kb2 * 8], ch1);
        float wh[8], wc[8];
        ldf8(W + kb2 * 8, wh);
        ldf8(W + 256 + kb2 * 8, wc);
#pragma unroll
        for (int i = 0; i < 8; ++i) {
          p0 = fmaf(hf0[i], wh[i], p0); p0 = fmaf(ch0[i], wc[i], p0);
          p1 = fmaf(hf1[i], wh[i], p1); p1 = fmaf(ch1[i], wc[i], p1);
        }
      }
    }
    if (kh) { part[0][n] = p0; part[1][n] = p1; }
    __syncthreads();
    if (kh == 0) {
      float q0 = (p0 + part[0][n] + Wy_b[n]) * vy_w[n];
      float q1 = (p1 + part[1][n] + Wy_b[n]) * vy_w[n];
#pragma unroll
      for (int off = 32; off; off >>= 1) {
        q0 += __shfl_xor(q0, off, 64);
        q1 += __shfl_xor(q1, off, 64);
      }
      if ((j & 63) == 0) { red[wv] = q0; red[4 + wv] = q1; }
    }
    __syncthreads();
    if (j == 0) {
      float o0 = red[0] + red[1] + red[2] + red[3] + vy_b[0];
      float o1 = red[4] + red[5] + red[6] + red[7] + vy_b[0];
      out[(size_t)outIdx * BB + b0] = o0;
      out[(size_t)outIdx * BB + b0 + 1] = o1;
      sc[0] = o0; sc[1] = o1;
    }
    __syncthreads();
  };

  // ================= scan over T steps =================
  for (int step = 0; step < TT; ++step) {
    // ---- stream: split-k, each weight H8 dotted vs both rows ----
    float sg0r0 = 0, sg0r1 = 0, sg1r0 = 0, sg1r1 = 0;
    float sg2r0 = 0, sg2r1 = 0, sg3r0 = 0, sg3r1 = 0;
    {
      float ax0 = 0.f, ax1 = 0.f;
      float g00 = 0, g01 = 0, g10 = 0, g11 = 0;
      float g20 = 0, g21 = 0, g30 = 0, g31 = 0;
      if (WQ) {
        const u16* Wd16 = (const u16*)Wd_q;
        const u16* Wh16 = (const u16*)Whh_q;
        const u16* pdh = Wd16 + (size_t)((kh * 16) * 256 + n) * 8;
        const u16* pdc = Wd16 + (size_t)((32 + kh * 16) * 256 + n) * 8;
        const u16* p0 = Wh16 + (size_t)((kh * 16) * 1024 + n) * 8;
        const u16* p1 = p0 + 256 * 8;
        const u16* p2 = p0 + 512 * 8;
        const u16* p3 = p0 + 768 * 8;
        const u32* hb0 = &hs16[0][kh * 64];
        const u32* hb1 = &hs16[1][kh * 64];
        const u32* cb0 = &hs16[0][128 + kh * 64];
        const u32* cb1 = &hs16[1][128 + kh * 64];
#pragma unroll 4
        for (int kb2 = 0; kb2 < 16; ++kb2) {
          H8 hp0 = *(const H8*)&hb0[kb2 * 4];
          H8 hp1 = *(const H8*)&hb1[kb2 * 4];
          H8 cp0 = *(const H8*)&cb0[kb2 * 4];
          H8 cp1 = *(const H8*)&cb1[kb2 * 4];
          H8 wdh = *(const H8*)pdh; pdh += 2048;
          H8 wdc = *(const H8*)pdc; pdc += 2048;
          H8 w0 = *(const H8*)p0; p0 += 8192;
          H8 w1 = *(const H8*)p1; p1 += 8192;
          H8 w2 = *(const H8*)p2; p2 += 8192;
          H8 w3 = *(const H8*)p3; p3 += 8192;
          ax0 = dot8(wdh, hp0, ax0); ax0 = dot8(wdc, cp0, ax0);
          ax1 = dot8(wdh, hp1, ax1); ax1 = dot8(wdc, cp1, ax1);
          g00 = dot8(w0, hp0, g00); g01 = dot8(w0, hp1, g01);
          g10 = dot8(w1, hp0, g10); g11 = dot8(w1, hp1, g11);
          g20 = dot8(w2, hp0, g20); g21 = dot8(w2, hp1, g21);
          g30 = dot8(w3, hp0, g30); g31 = dot8(w3, hp1, g31);
        }
      } else {
        const float* wdp = (const float*)Wd_q + (size_t)n * 512 + kh * 128;
        const float* w0p = (const float*)Whh_q + (size_t)n * 256 + kh * 128;
#pragma unroll 2
        for (int kb2 = 0; kb2 < 16; ++kb2) {
          H8 hp0v = *(const H8*)&hs16[0][kh * 64 + kb2 * 4];
          H8 hp1v = *(const H8*)&hs16[1][kh * 64 + kb2 * 4];
          H8 cp0v = *(const H8*)&hs16[0][128 + kh * 64 + kb2 * 4];
          H8 cp1v = *(const H8*)&hs16[1][128 + kh * 64 + kb2 * 4];
          float hf0[8], hf1[8], cf0[8], cf1[8];
          unpackH8(hp0v, hf0); unpackH8(hp1v, hf1);
          unpackH8(cp0v, cf0); unpackH8(cp1v, cf1);
          float wh[8], wc[8], w0[8], w1[8], w2[8], w3[8];
          ldf8(wdp + kb2 * 8, wh);
          ldf8(wdp + 256 + kb2 * 8, wc);
          ldf8(w0p + kb2 * 8, w0);
          ldf8(w0p + 256 * 256 + kb2 * 8, w1);
          ldf8(w0p + 512 * 256 + kb2 * 8, w2);
          ldf8(w0p + 768 * 256 + kb2 * 8, w3);
#pragma unroll
          for (int i = 0; i < 8; ++i) {
            ax0 = fmaf(hf0[i], wh[i], ax0); ax0 = fmaf(cf0[i], wc[i], ax0);
            ax1 = fmaf(hf1[i], wh[i], ax1); ax1 = fmaf(cf1[i], wc[i], ax1);
            g00 = fmaf(hf0[i], w0[i], g00); g01 = fmaf(hf1[i], w0[i], g01);
            g10 = fmaf(hf0[i], w1[i], g10); g11 = fmaf(hf1[i], w1[i], g11);
            g20 = fmaf(hf0[i], w2[i], g20); g21 = fmaf(hf1[i], w2[i], g21);
            g30 = fmaf(hf0[i], w3[i], g30); g31 = fmaf(hf1[i], w3[i], g31);
          }
        }
      }
      if (kh) {
        x1b[0][n] = ax0; x1b[1][n] = ax1;
        part[2][n] = g00; part[3][n] = g01;
        part[4][n] = g10; part[5][n] = g11;
        part[6][n] = g20; part[7][n] = g21;
        part[8][n] = g30; part[9][n] = g31;
      } else {
        float bia = Wd_b[n];
        x1a[0][n] = ax0 + bia; x1a[1][n] = ax1 + bia;
        sg0r0 = g00; sg0r1 = g01; sg1r0 = g10; sg1r1 = g11;
        sg2r0 = g20; sg2r1 = g21; sg3r0 = g30; sg3r1 = g31;
      }
    }
    __syncthreads();

    // ---- B1: l[t] quarter-partials; thread = (r=kh, q, t) ----
    {
      const int q = (j >> 6) & 3, tq = j & 63;
      const u16* __restrict__ yrow = &y1l[kh][tq * YS + q * 64];
      const float* __restrict__ xap = &x1a[kh][q * 64];
      const float* __restrict__ xbp = &x1b[kh][q * 64];
      const float* __restrict__ vp = vd_w + q * 64;
      float lp = 0.f;
#pragma unroll 2
      for (int m0 = 0; m0 < 64; m0 += 8) {
        H8 yv = *(const H8*)(yrow + m0);
        float yf[8]; unpackH8(yv, yf);
        float xf[8]; ldf8(xap + m0, xf);
        float xg[8]; ldf8(xbp + m0, xg);
        float vf[8]; ldf8(vp + m0, vf);
#pragma unroll
        for (int mm = 0; mm < 8; ++mm) {
          float z = tanh_fast(xf[mm] + xg[mm] + yf[mm]);
          lp = fmaf(z, vf[mm], lp);
        }
      }
      lpart[kh][q][tq] = lp;
    }
    __syncthreads();

    // ---- softmax over t (waves 0 and 4, one per row) -> betas16 ----
    if (n < 64) {
      const int t = n;
      float l = lpart[kh][0][t] + lpart[kh][1][t] + lpart[kh][2][t] +
                lpart[kh][3][t];
      float mx = l;
#pragma unroll
      for (int off = 32; off; off >>= 1) mx = fmaxf(mx, __shfl_xor(mx, off, 64));
      float e = __builtin_amdgcn_exp2f((l - mx) * 1.4426950408889634f);
      float sm = e;
#pragma unroll
      for (int off = 32; off; off >>= 1) sm += __shfl_xor(sm, off, 64);
      betas16[kh][t] = f2h(e * __builtin_amdgcn_rcpf(sm));
    }
    __syncthreads();

    // ---- B2: ct[m] = sum_t beta[t]*E[t][m]; + ytil partial reduce ----
    {
      const u16* __restrict__ ep = &e16T[kh][n * ES];
      float acc = 0.f;
#pragma unroll
      for (int t0 = 0; t0 < TT; t0 += 8) {
        h2 e0 = *(const h2*)(ep + t0);
        h2 e1 = *(const h2*)(ep + t0 + 2);
        h2 e2 = *(const h2*)(ep + t0 + 4);
        h2 e3 = *(const h2*)(ep + t0 + 6);
        H8 bp = *(const H8*)&betas16[kh][t0];
        acc = FDOT2(bp.p[0], e0, acc);
        acc = FDOT2(bp.p[1], e1, acc);
        acc = FDOT2(bp.p[2], e2, acc);
        acc = FDOT2(bp.p[3], e3, acc);
      }
      ctx[kh][n] = acc;
      ((u16*)ctx16p[kh])[n] = f2h(acc);
      float p = acc * wt_w[n];
#pragma unroll
      for (int off = 32; off; off >>= 1) p += __shfl_xor(p, off, 64);
      if ((j & 63) == 0) red[wv] = p;
    }
    __syncthreads();

    // ---- combine gate partials + gates (kh==0 threads, both rows) ----
    if (kh == 0) {
      float yt0 = red[0] + red[1] + red[2] + red[3] +
                  yin[(size_t)b0 * TT + step] * wtM + wtb;
      float yt1 = red[4] + red[5] + red[6] + red[7] +
                  yin[(size_t)(b0 + 1) * TT + step] * wtM + wtb;
      gates_apply(0, sg0r0 + part[2][n], sg1r0 + part[4][n],
                  sg2r0 + part[6][n], sg3r0 + part[8][n], yt0);
      gates_apply(1, sg0r1 + part[3][n], sg1r1 + part[5][n],
                  sg2r1 + part[7][n], sg3r1 + part[9][n], yt1);
    }
    __syncthreads();
  }

  // ================= finals =================
  {
    float p = ctx[kh][n] * wt_w[n];
#pragma unroll
    for (int off = 32; off; off >>= 1) p += __shfl_xor(p, off, 64);
    if ((j & 63) == 0) red[wv] = p;
  }
  __syncthreads();
  const float ctdot0 = red[0] + red[1] + red[2] + red[3];
  const float ctdot1 = red[4] + red[5] + red[6] + red[7];

  head_store(0);  // y_Tp1 (sc[] holds it for train==0 feedback)

  const int tr = train[0];
  for (int e = 0; e < 2; ++e) {
    // ---- mv4: Whh @ h, split-k, both rows ----
    float g00 = 0, g01 = 0, g10 = 0, g11 = 0;
    float g20 = 0, g21 = 0, g30 = 0, g31 = 0;
    if (WQ) {
      const u16* Wh16 = (const u16*)Whh_q;
      const u16* p0 = Wh16 + (size_t)((kh * 16) * 1024 + n) * 8;
      const u16* p1 = p0 + 256 * 8;
      const u16* p2 = p0 + 512 * 8;
      const u16* p3 = p0 + 768 * 8;
      const u32* hb0 = &hs16[0][kh * 64];
      const u32* hb1 = &hs16[1][kh * 64];
#pragma unroll 4
      for (int kb2 = 0; kb2 < 16; ++kb2) {
        H8 hp0 = *(const H8*)&hb0[kb2 * 4];
        H8 hp1 = *(const H8*)&hb1[kb2 * 4];
        H8 w0 = *(const H8*)p0; p0 += 8192;
        H8 w1 = *(const H8*)p1; p1 += 8192;
        H8 w2 = *(const H8*)p2; p2 += 8192;
        H8 w3 = *(const H8*)p3; p3 += 8192;
        g00 = dot8(w0, hp0, g00); g01 = dot8(w0, hp1, g01);
        g10 = dot8(w1, hp0, g10); g11 = dot8(w1, hp1, g11);
        g20 = dot8(w2, hp0, g20); g21 = dot8(w2, hp1, g21);
        g30 = dot8(w3, hp0, g30); g31 = dot8(w3, hp1, g31);
      }
    } else {
      const float* w0p = (const float*)Whh_q + (size_t)n * 256 + kh * 128;
#pragma unroll 2
      for (int kb2 = 0; kb2 < 16; ++kb2) {
        H8 hp0v = *(const H8*)&hs16[0][kh * 64 + kb2 * 4];
        H8 hp1v = *(const H8*)&hs16[1][kh * 64 + kb2 * 4];
        float hf0[8], hf1[8]; unpackH8(hp0v, hf0); unpackH8(hp1v, hf1);
        float w0[8], w1[8], w2[8], w3[8];
        ldf8(w0p + kb2 * 8, w0);
        ldf8(w0p + 256 * 256 + kb2 * 8, w1);
        ldf8(w0p + 512 * 256 + kb2 * 8, w2);
        ldf8(w0p + 768 * 256 + kb2 * 8, w3);
#pragma unroll
        for (int i = 0; i < 8; ++i) {
          g00 = fmaf(hf0[i], w0[i], g00); g01 = fmaf(hf1[i], w0[i], g01);
          g10 = fmaf(hf0[i], w1[i], g10); g11 = fmaf(hf1[i], w1[i], g11);
          g20 = fmaf(hf0[i], w2[i], g20); g21 = fmaf(hf1[i], w2[i], g21);
          g30 = fmaf(hf0[i], w3[i], g30); g31 = fmaf(hf1[i], w3[i], g31);
        }
      }
    }
    if (kh) {
      part[2][n] = g00; part[3][n] = g01;
      part[4][n] = g10; part[5][n] = g11;
      part[6][n] = g20; part[7][n] = g21;
      part[8][n] = g30; part[9][n] = g31;
    }
    __syncthreads();
    if (kh == 0) {
      float inp0 = tr ? tar[(size_t)b0 * 2 + e] : sc[0];
      float inp1 = tr ? tar[(size_t)(b0 + 1) * 2 + e] : sc[1];
      float yt0 = ctdot0 + inp0 * wtM + wtb;
      float yt1 = ctdot1 + inp1 * wtM + wtb;
      gates_apply(0, g00 + part[2][n], g10 + part[4][n],
                  g20 + part[6][n], g30 + part[8][n], yt0);
      gates_apply(1, g01 + part[3][n], g11 + part[5][n],
                  g21 + part[7][n], g31 + part[9][n], yt1);
    }
    __syncthreads();
    head_store(1 + e);
  }
}

extern "C" void kernel_launch(void* const* d_in, const int* in_sizes, int n_in,
                              void* d_out, int out_size, void* d_ws, size_t ws_size,
                              hipStream_t stream) {
  const float* E     = (const float*)d_in[0];
  const float* yin   = (const float*)d_in[1];
  const float* tar   = (const float*)d_in[2];
  const int*   train = (const int*)d_in[3];
  const float* Wd_w  = (const float*)d_in[4];
  const float* Wd_b  = (const float*)d_in[5];
  const float* Ud_w  = (const float*)d_in[6];
  const float* vd_w  = (const float*)d_in[7];
  const float* wt_w  = (const float*)d_in[8];
  const float* wt_b  = (const float*)d_in[9];
  const float* Wy_w  = (const float*)d_in[10];
  const float* Wy_b  = (const float*)d_in[11];
  const float* vy_w  = (const float*)d_in[12];
  const float* vy_b  = (const float*)d_in[13];
  const float* Wih   = (const float*)d_in[14];
  const float* Whh   = (const float*)d_in[15];
  const float* bih   = (const float*)d_in[16];
  const float* bhh   = (const float*)d_in[17];

  float* out = (float*)d_out;

  if (ws_size >= (size_t)WQ_BYTES) {
    u16* wq = (u16*)d_ws;
    prep_kernel<<<dim3(WQ_ELEMS / 256), dim3(256), 0, stream>>>(
        Wd_w, Whh, Wy_w, wq);
    scan_kernel<1><<<dim3(BB / NROW), dim3(NTH), 0, stream>>>(
        E, yin, tar, train, wq + WD16_OFF, Wd_b, Ud_w, vd_w, wt_w, wt_b,
        wq + WY16_OFF, Wy_b, vy_w, vy_b, Wih, wq + WHH16_OFF, bih, bhh, out);
  } else {
    scan_kernel<0><<<dim3(BB / NROW), dim3(NTH), 0, stream>>>(
        E, yin, tar, train, Wd_w, Wd_b, Ud_w, vd_w, wt_w, wt_b,
        Wy_w, Wy_b, vy_w, vy_b, Wih, Whh, bih, bhh, out);
  }

  (void)in_sizes; (void)n_in; (void)out_size;
}

// Round 2
// 1087.354 us; speedup vs baseline: 1.0966x; 1.0126x over previous
//
#include <hip/hip_runtime.h>

// TemporalAttentionDecoder_three_step: B=512, T=64, M=P=256. in f32, out f32.
// R9:  1120us. VALU 47%, occ 24% (8 waves/CU). L2 halved vs R8 but wave count
//      unchanged -> latency-bound: 53% of time is barrier/L2-latency stall
//      with only 2 waves/SIMD to hide it.
// R10: 1024 threads/block (16 waves/CU = 4/SIMD), NROW=2, grid 256. 4-group
//      split keeps every weight H8 read ONCE per block per step (L2 stays
//      12.6GB): grp0/1 = gates i,f,g k-halves (dot both rows);
//      grp2/3 = Wd(x1) k-halves + gate o k-halves (dot both rows).
//      Partials: x1 (4 arrays) summed in B1; i/f/g (grp1) + o (grp2/3)
//      combined in gates phase -> still 5 barriers/step. ctx f32 dropped
//      (ytil/ctdot use f16 ct, same as head) to fit LDS 159.5KB.
// f32 state: creg (grp0 regs); f16: h,c,y1,E,ct,weights; dots accumulate f32.

typedef unsigned short u16;
typedef unsigned int u32;
typedef _Float16 half_t;
typedef half_t h2 __attribute__((ext_vector_type(2)));

#define BB 512
#define TT 64
#define MM 256
#define PP 256
#define YS 264   // y1l row stride (u16); measured conflict-free (R6/R7)
#define ES 68    // e16T row stride (u16); 2-way (free)
#define NROW 2
#define NTH 1024

// ws layout (u16), all k-blocked n-major [kb][n][8]:
//   WdT8 [64kb][256n][8]  @ 0       (131072)
//   WhhT8[32kb][1024n][8] @ 131072  (262144)
//   WyT8 [64kb][256n][8]  @ 393216  (131072)
#define WD16_OFF  0
#define WHH16_OFF 131072
#define WY16_OFF  393216
#define WQ_ELEMS  524288
#define WQ_BYTES  (WQ_ELEMS * 2)

struct H8 { h2 p[4]; };   // 16B = 8 f16

#if defined(__has_builtin)
#if __has_builtin(__builtin_amdgcn_fdot2)
#define FDOT2(a, b, c) __builtin_amdgcn_fdot2((a), (b), (c), false)
#endif
#endif
#ifndef FDOT2
__device__ __forceinline__ float FDOT2(h2 a, h2 b, float c) {
  return c + (float)a[0] * (float)b[0] + (float)a[1] * (float)b[1];
}
#endif

__device__ __forceinline__ float dot8(const H8 w, const H8 a, float acc) {
  acc = FDOT2(w.p[0], a.p[0], acc);
  acc = FDOT2(w.p[1], a.p[1], acc);
  acc = FDOT2(w.p[2], a.p[2], acc);
  acc = FDOT2(w.p[3], a.p[3], acc);
  return acc;
}
__device__ __forceinline__ u16 f2h(float f) {
  union { half_t h; u16 u; } x; x.h = (half_t)f; return x.u;
}
__device__ __forceinline__ float h2f(u16 u) {
  union { u16 u; half_t h; } x; x.u = u; return (float)x.h;
}
__device__ __forceinline__ void unpackH8(const H8 v, float f[8]) {
#pragma unroll
  for (int i = 0; i < 8; ++i) f[i] = (float)v.p[i >> 1][i & 1];
}
__device__ __forceinline__ void ldf8(const float* p, float f[8]) {
  float4 a = *(const float4*)p;
  float4 b = *(const float4*)(p + 4);
  f[0]=a.x; f[1]=a.y; f[2]=a.z; f[3]=a.w;
  f[4]=b.x; f[5]=b.y; f[6]=b.z; f[7]=b.w;
}
__device__ __forceinline__ float tanh_fast(float x) {
  float e = __builtin_amdgcn_exp2f(x * 2.885390081777927f);
  return 1.0f - 2.0f * __builtin_amdgcn_rcpf(1.0f + e);
}
__device__ __forceinline__ float sigmoid_fast(float x) {
  float e = __builtin_amdgcn_exp2f(x * -1.4426950408889634f);
  return __builtin_amdgcn_rcpf(1.0f + e);
}

// ---- prep: f32 -> f16, k-blocked n-major ----
__global__ __launch_bounds__(256) void prep_kernel(
    const float* __restrict__ Wd, const float* __restrict__ Whh,
    const float* __restrict__ Wy, u16* __restrict__ o) {
  int i = blockIdx.x * 256 + threadIdx.x;   // 0..524287
  float v;
  if (i < WHH16_OFF) {
    int ki = i & 7, n = (i >> 3) & 255, kb = i >> 11;
    v = Wd[n * 512 + kb * 8 + ki];
  } else if (i < WY16_OFF) {
    int r = i - WHH16_OFF;
    int ki = r & 7, n = (r >> 3) & 1023, kb = r >> 13;
    v = Whh[n * 256 + kb * 8 + ki];
  } else {
    int r = i - WY16_OFF;
    int ki = r & 7, n = (r >> 3) & 255, kb = r >> 11;
    v = Wy[n * 512 + kb * 8 + ki];
  }
  o[i] = f2h(v);
}

template <int WQ>
__global__ __launch_bounds__(NTH, 4) void scan_kernel(
    const float* __restrict__ E,      // (B,T,M)
    const float* __restrict__ yin,    // (B,T,1)
    const float* __restrict__ tar,    // (B,2)
    const int*   __restrict__ train,  // (1)
    const void*  __restrict__ Wd_q,   // WQ1: WdT8 f16 | WQ0: f32 row-major
    const float* __restrict__ Wd_b,
    const float* __restrict__ Ud_w,   // (256,256) f32
    const float* __restrict__ vd_w,
    const float* __restrict__ wt_w,   // (257)
    const float* __restrict__ wt_b,
    const void*  __restrict__ Wy_q,
    const float* __restrict__ Wy_b,
    const float* __restrict__ vy_w,
    const float* __restrict__ vy_b,
    const float* __restrict__ Wih,    // (1024)
    const void*  __restrict__ Whh_q,
    const float* __restrict__ bih,
    const float* __restrict__ bhh,
    float* __restrict__ out)          // (3*B)
{
  __shared__ __align__(16) u16   y1l[NROW][TT * YS];   // 66KB f16 y1
  __shared__ __align__(16) u16   e16T[NROW][MM * ES];  // 68KB f16 E^T
  __shared__ __align__(16) u32   hs16[NROW][256];      // h pairs [0,128), c [128,256)
  __shared__ __align__(16) u32   ctx16p[NROW][128];    // ct f16 pairs
  __shared__ __align__(16) float px1[4][MM];   // x1: [0]=h r0+b, [1]=h r1+b, [2]=c r0, [3]=c r1
  __shared__ __align__(16) float pg[6][MM];    // grp1: i r0,i r1,f r0,f r1,g r0,g r1
  __shared__ __align__(16) float pg3[4][MM];   // o: grp2(r0,r1), grp3(r0,r1)
  __shared__ __align__(16) float lpart[NROW][8][TT];
  __shared__ __align__(16) u16   betas16[NROW][TT];
  __shared__ __align__(16) float ysh[NROW][TT];
  __shared__ float red[16];
  __shared__ float sc[NROW];

  const int j   = threadIdx.x;         // 0..1023
  const int n   = j & 255;             // output index
  const int grp = j >> 8;              // group 0..3 (wave-aligned: 4 waves each)
  const int wv  = j >> 6;              // wave 0..15
  const int b0  = blockIdx.x * NROW;   // batch rows b0, b0+1

  if (j < 512) ((u32*)hs16)[j] = 0;
  float creg0 = 0.f, creg1 = 0.f;      // live in grp0 threads

  // gate constants (consumed by grp0)
  const float wih0 = Wih[n],       wih1 = Wih[n + 256];
  const float wih2 = Wih[n + 512], wih3 = Wih[n + 768];
  const float bb0 = bih[n]       + bhh[n];
  const float bb1 = bih[n + 256] + bhh[n + 256];
  const float bb2 = bih[n + 512] + bhh[n + 512];
  const float bb3 = bih[n + 768] + bhh[n + 768];
  const float wtM = wt_w[MM], wtb = wt_b[0];

  // ---- stage yin rows ----
  if (j < NROW * TT)
    ysh[j >> 6][j & 63] = yin[(size_t)(b0 + (j >> 6)) * TT + (j & 63)];

  // ---- stage E^T (f16) into LDS for both rows ----
  {
    const float* __restrict__ Eb0 = E + (size_t)b0 * TT * MM;
    for (int i = j; i < NROW * TT * MM; i += NTH) {
      int r = i >> 14;
      int idx = i & 16383;
      int t = idx >> 8, m = idx & 255;
      e16T[r][m * ES + t] = f2h(Eb0[i]);
    }
  }

  // ---- y1 into LDS: thread (grp,n): row grp>>1, t-half grp&1, column n ----
  {
    const int rs = grp >> 1, ths = grp & 1;
    const float* __restrict__ Eb = E + (size_t)(b0 + rs) * TT * MM;
    const float* __restrict__ Uj = Ud_w + (size_t)n * MM;
    for (int t0 = ths * 32; t0 < ths * 32 + 32; t0 += 16) {
      float acc[16];
#pragma unroll
      for (int i = 0; i < 16; ++i) acc[i] = 0.f;
      for (int m0 = 0; m0 < MM; m0 += 8) {
        float w[8]; ldf8(Uj + m0, w);
#pragma unroll
        for (int tt = 0; tt < 16; ++tt) {
          float e[8]; ldf8(Eb + (size_t)(t0 + tt) * MM + m0, e);
#pragma unroll
          for (int mm = 0; mm < 8; ++mm) acc[tt] = fmaf(e[mm], w[mm], acc[tt]);
        }
      }
#pragma unroll
      for (int tt = 0; tt < 16; ++tt)
        y1l[rs][(t0 + tt) * YS + n] = f2h(acc[tt]);
    }
  }
  __syncthreads();

  // ---- gates: torch LSTMCell order i,f,g,o; grp0 threads, both rows ----
  auto gates_apply = [&](int r, float gi, float gf, float gg, float go,
                         float ytil) {
    gi += ytil * wih0 + bb0;
    gf += ytil * wih1 + bb1;
    gg += ytil * wih2 + bb2;
    go += ytil * wih3 + bb3;
    float& cr = r ? creg1 : creg0;
    float c = sigmoid_fast(gf) * cr + sigmoid_fast(gi) * tanh_fast(gg);
    float h = sigmoid_fast(go) * tanh_fast(c);
    cr = c;
    u16* hsu = (u16*)hs16[r];
    hsu[n] = f2h(h);
    hsu[256 + n] = f2h(c);
  };

  // ---- head: grp = (row<<1)|seg; seg0 = h-seg, seg1 = ct-seg ----
  auto head_store = [&](int outIdx) {
    float p = 0.f;
    const int rr = grp >> 1, seg = grp & 1;
    const u32* st = seg ? ctx16p[rr] : hs16[rr];
    if (WQ) {
      const u16* pw = (const u16*)Wy_q + ((size_t)(seg * 32) * 256 + n) * 8;
#pragma unroll 2
      for (int kb = 0; kb < 32; ++kb) {
        H8 w = *(const H8*)pw; pw += 2048;
        H8 s = *(const H8*)&st[kb * 4];
        p = dot8(w, s, p);
      }
    } else {
      const float* W = (const float*)Wy_q + (size_t)n * 512 + seg * 256;
#pragma unroll 2
      for (int kb = 0; kb < 32; ++kb) {
        H8 sv = *(const H8*)&st[kb * 4];
        float sf[8]; unpackH8(sv, sf);
        float w[8]; ldf8(W + kb * 8, w);
#pragma unroll
        for (int i = 0; i < 8; ++i) p = fmaf(sf[i], w[i], p);
      }
    }
    if (grp) px1[grp - 1][n] = p;   // px1 free after scan; reuse as head parts
    __syncthreads();
    if (grp == 0) {
      float q0 = (p + px1[0][n] + Wy_b[n]) * vy_w[n];
      float q1 = (px1[1][n] + px1[2][n] + Wy_b[n]) * vy_w[n];
#pragma unroll
      for (int off = 32; off; off >>= 1) {
        q0 += __shfl_xor(q0, off, 64);
        q1 += __shfl_xor(q1, off, 64);
      }
      if ((j & 63) == 0) { red[wv] = q0; red[8 + wv] = q1; }
    }
    __syncthreads();
    if (j == 0) {
      float o0 = red[0] + red[1] + red[2] + red[3] + vy_b[0];
      float o1 = red[8] + red[9] + red[10] + red[11] + vy_b[0];
      out[(size_t)outIdx * BB + b0] = o0;
      out[(size_t)outIdx * BB + b0 + 1] = o1;
      sc[0] = o0; sc[1] = o1;
    }
    __syncthreads();
  };

  // ---- mv4: Whh@h both rows, same group split as stream (no Wd) ----
  auto mv4 = [&](float& m0, float& m1, float& m2, float& m3, float& m4,
                 float& m5) {
    m0 = m1 = m2 = m3 = m4 = m5 = 0.f;
    if (WQ) {
      const u16* Whh16 = (const u16*)Whh_q;
      if (grp < 2) {
        const int kb0 = grp << 4;
        const u16* pw = Whh16 + ((size_t)kb0 * 1024 + n) * 8;
#pragma unroll 2
        for (int kb2 = 0; kb2 < 16; ++kb2) {
          const int kb = kb0 + kb2;
          H8 h0 = *(const H8*)&hs16[0][kb * 4];
          H8 h1 = *(const H8*)&hs16[1][kb * 4];
          H8 w0 = *(const H8*)pw;
          H8 w1 = *(const H8*)(pw + 2048);
          H8 w2 = *(const H8*)(pw + 4096);
          pw += 8192;
          m0 = dot8(w0, h0, m0); m1 = dot8(w0, h1, m1);
          m2 = dot8(w1, h0, m2); m3 = dot8(w1, h1, m3);
          m4 = dot8(w2, h0, m4); m5 = dot8(w2, h1, m5);
        }
      } else {
        const int half = grp - 2;
        const u16* p3 = Whh16 + ((size_t)(half * 16) * 1024 + 768 + n) * 8;
#pragma unroll 2
        for (int kb2 = 0; kb2 < 16; ++kb2) {
          const int kg = half * 16 + kb2;
          H8 w3 = *(const H8*)p3; p3 += 8192;
          H8 h0 = *(const H8*)&hs16[0][kg * 4];
          H8 h1 = *(const H8*)&hs16[1][kg * 4];
          m0 = dot8(w3, h0, m0); m1 = dot8(w3, h1, m1);
        }
      }
    } else {
      const float* Whf = (const float*)Whh_q;
      if (grp < 2) {
        const int kb0 = grp << 4;
        const float* pw0 = Whf + (size_t)n * 256 + kb0 * 8;
        const float* pw1 = pw0 + 256 * 256;
        const float* pw2 = pw0 + 512 * 256;
#pragma unroll 2
        for (int kb2 = 0; kb2 < 16; ++kb2) {
          const int kb = kb0 + kb2;
          H8 h0v = *(const H8*)&hs16[0][kb * 4];
          H8 h1v = *(const H8*)&hs16[1][kb * 4];
          float hf0[8], hf1[8]; unpackH8(h0v, hf0); unpackH8(h1v, hf1);
          float w0[8], w1[8], w2[8];
          ldf8(pw0 + kb2 * 8, w0);
          ldf8(pw1 + kb2 * 8, w1);
          ldf8(pw2 + kb2 * 8, w2);
#pragma unroll
          for (int i = 0; i < 8; ++i) {
            m0 = fmaf(hf0[i], w0[i], m0); m1 = fmaf(hf1[i], w0[i], m1);
            m2 = fmaf(hf0[i], w1[i], m2); m3 = fmaf(hf1[i], w1[i], m3);
            m4 = fmaf(hf0[i], w2[i], m4); m5 = fmaf(hf1[i], w2[i], m5);
          }
        }
      } else {
        const int half = grp - 2;
        const float* p3f = Whf + ((size_t)(768 + n)) * 256 + half * 128;
#pragma unroll 2
        for (int kb2 = 0; kb2 < 16; ++kb2) {
          const int kg = half * 16 + kb2;
          H8 h0v = *(const H8*)&hs16[0][kg * 4];
          H8 h1v = *(const H8*)&hs16[1][kg * 4];
          float hf0[8], hf1[8]; unpackH8(h0v, hf0); unpackH8(h1v, hf1);
          float w3[8]; ldf8(p3f + kb2 * 8, w3);
#pragma unroll
          for (int i = 0; i < 8; ++i) {
            m0 = fmaf(hf0[i], w3[i], m0); m1 = fmaf(hf1[i], w3[i], m1);
          }
        }
      }
    }
  };

  // ================= scan over T steps =================
  for (int step = 0; step < TT; ++step) {
    // ---- stream: 4-group split, every weight H8 read once per block ----
    float s0 = 0.f, s1 = 0.f, s2 = 0.f, s3 = 0.f, s4 = 0.f, s5 = 0.f;
    {
      float a0 = 0, a1 = 0, a2 = 0, a3 = 0, a4 = 0, a5 = 0;
      if (WQ) {
        const u16* Whh16 = (const u16*)Whh_q;
        if (grp < 2) {
          // gates i,f,g; k-half kb0..kb0+15; both rows
          const int kb0 = grp << 4;
          const u16* pw = Whh16 + ((size_t)kb0 * 1024 + n) * 8;
#pragma unroll 2
          for (int kb2 = 0; kb2 < 16; ++kb2) {
            const int kb = kb0 + kb2;
            H8 h0 = *(const H8*)&hs16[0][kb * 4];
            H8 h1 = *(const H8*)&hs16[1][kb * 4];
            H8 w0 = *(const H8*)pw;
            H8 w1 = *(const H8*)(pw + 2048);
            H8 w2 = *(const H8*)(pw + 4096);
            pw += 8192;
            a0 = dot8(w0, h0, a0); a1 = dot8(w0, h1, a1);
            a2 = dot8(w1, h0, a2); a3 = dot8(w1, h1, a3);
            a4 = dot8(w2, h0, a4); a5 = dot8(w2, h1, a5);
          }
        } else {
          // Wd k-half (x1, both rows) + gate o k-half (both rows)
          const int half = grp - 2;
          const u16* pd = (const u16*)Wd_q + ((size_t)(half * 32) * 256 + n) * 8;
          const u16* p3 = Whh16 + ((size_t)(half * 16) * 1024 + 768 + n) * 8;
#pragma unroll 2
          for (int kb2 = 0; kb2 < 16; ++kb2) {
            const int kd = half * 32 + kb2 * 2;   // hs16 [h|c] contiguous
            const int kg = half * 16 + kb2;
            H8 s00 = *(const H8*)&hs16[0][kd * 4];
            H8 s01 = *(const H8*)&hs16[0][kd * 4 + 4];
            H8 s10 = *(const H8*)&hs16[1][kd * 4];
            H8 s11 = *(const H8*)&hs16[1][kd * 4 + 4];
            H8 wd0 = *(const H8*)pd;
            H8 wd1 = *(const H8*)(pd + 2048);
            pd += 4096;
            H8 w3 = *(const H8*)p3; p3 += 8192;
            H8 h0 = *(const H8*)&hs16[0][kg * 4];
            H8 h1 = *(const H8*)&hs16[1][kg * 4];
            a0 = dot8(wd0, s00, a0); a0 = dot8(wd1, s01, a0);
            a1 = dot8(wd0, s10, a1); a1 = dot8(wd1, s11, a1);
            a2 = dot8(w3, h0, a2);   a3 = dot8(w3, h1, a3);
          }
        }
      } else {
        const float* Whf = (const float*)Whh_q;
        if (grp < 2) {
          const int kb0 = grp << 4;
          const float* pw0 = Whf + (size_t)n * 256 + kb0 * 8;
          const float* pw1 = pw0 + 256 * 256;
          const float* pw2 = pw0 + 512 * 256;
#pragma unroll 2
          for (int kb2 = 0; kb2 < 16; ++kb2) {
            const int kb = kb0 + kb2;
            H8 h0v = *(const H8*)&hs16[0][kb * 4];
            H8 h1v = *(const H8*)&hs16[1][kb * 4];
            float hf0[8], hf1[8]; unpackH8(h0v, hf0); unpackH8(h1v, hf1);
            float w0[8], w1[8], w2[8];
            ldf8(pw0 + kb2 * 8, w0);
            ldf8(pw1 + kb2 * 8, w1);
            ldf8(pw2 + kb2 * 8, w2);
#pragma unroll
            for (int i = 0; i < 8; ++i) {
              a0 = fmaf(hf0[i], w0[i], a0); a1 = fmaf(hf1[i], w0[i], a1);
              a2 = fmaf(hf0[i], w1[i], a2); a3 = fmaf(hf1[i], w1[i], a3);
              a4 = fmaf(hf0[i], w2[i], a4); a5 = fmaf(hf1[i], w2[i], a5);
            }
          }
        } else {
          const int half = grp - 2;
          const float* Wdf = (const float*)Wd_q + (size_t)n * 512 + half * 256;
          const float* p3f = Whf + ((size_t)(768 + n)) * 256 + half * 128;
#pragma unroll 2
          for (int kb2 = 0; kb2 < 16; ++kb2) {
            const int kd = half * 32 + kb2 * 2;
            const int kg = half * 16 + kb2;
            H8 s00v = *(const H8*)&hs16[0][kd * 4];
            H8 s01v = *(const H8*)&hs16[0][kd * 4 + 4];
            H8 s10v = *(const H8*)&hs16[1][kd * 4];
            H8 s11v = *(const H8*)&hs16[1][kd * 4 + 4];
            float f00[8], f01[8], f10[8], f11[8];
            unpackH8(s00v, f00); unpackH8(s01v, f01);
            unpackH8(s10v, f10); unpackH8(s11v, f11);
            H8 h0v = *(const H8*)&hs16[0][kg * 4];
            H8 h1v = *(const H8*)&hs16[1][kg * 4];
            float hf0[8], hf1[8]; unpackH8(h0v, hf0); unpackH8(h1v, hf1);
            float wd0[8], wd1[8], w3[8];
            ldf8(Wdf + kb2 * 16, wd0);
            ldf8(Wdf + kb2 * 16 + 8, wd1);
            ldf8(p3f + kb2 * 8, w3);
#pragma unroll
            for (int i = 0; i < 8; ++i) {
              a0 = fmaf(f00[i], wd0[i], a0); a0 = fmaf(f01[i], wd1[i], a0);
              a1 = fmaf(f10[i], wd0[i], a1); a1 = fmaf(f11[i], wd1[i], a1);
              a2 = fmaf(hf0[i], w3[i], a2);  a3 = fmaf(hf1[i], w3[i], a3);
            }
          }
        }
      }
      if (grp == 0) {
        s0 = a0; s1 = a1; s2 = a2; s3 = a3; s4 = a4; s5 = a5;
      } else if (grp == 1) {
        pg[0][n] = a0; pg[1][n] = a1; pg[2][n] = a2;
        pg[3][n] = a3; pg[4][n] = a4; pg[5][n] = a5;
      } else if (grp == 2) {
        float bia = Wd_b[n];
        px1[0][n] = a0 + bia; px1[1][n] = a1 + bia;
        pg3[0][n] = a2; pg3[1][n] = a3;
      } else {
        px1[2][n] = a0; px1[3][n] = a1;
        pg3[2][n] = a2; pg3[3][n] = a3;
      }
    }
    __syncthreads();

    // ---- B1: l[t] eighth-partials; thread = (r, e8, t); 32 m each ----
    {
      const int r = j >> 9, e8 = (j >> 6) & 7, t = j & 63;
      const u16* __restrict__ yrow = &y1l[r][t * YS + e8 * 32];
      const float* __restrict__ xh = &px1[r][e8 * 32];
      const float* __restrict__ xc = &px1[2 + r][e8 * 32];
      const float* __restrict__ vp = vd_w + e8 * 32;
      float lp = 0.f;
#pragma unroll
      for (int m0 = 0; m0 < 32; m0 += 8) {
        H8 yv = *(const H8*)(yrow + m0);
        float yf[8]; unpackH8(yv, yf);
        float xf[8]; ldf8(xh + m0, xf);
        float xg[8]; ldf8(xc + m0, xg);
        float vf[8]; ldf8(vp + m0, vf);
#pragma unroll
        for (int mm = 0; mm < 8; ++mm) {
          float z = tanh_fast(xf[mm] + xg[mm] + yf[mm]);
          lp = fmaf(z, vf[mm], lp);
        }
      }
      lpart[r][e8][t] = lp;
    }
    __syncthreads();

    // ---- softmax over t (waves 0 and 8, one per row) -> betas16 ----
    if ((j & 511) < 64) {
      const int r = j >> 9, t = j & 63;
      float l = lpart[r][0][t] + lpart[r][1][t] + lpart[r][2][t] +
                lpart[r][3][t] + lpart[r][4][t] + lpart[r][5][t] +
                lpart[r][6][t] + lpart[r][7][t];
      float mx = l;
#pragma unroll
      for (int off = 32; off; off >>= 1) mx = fmaxf(mx, __shfl_xor(mx, off, 64));
      float e = __builtin_amdgcn_exp2f((l - mx) * 1.4426950408889634f);
      float sm = e;
#pragma unroll
      for (int off = 32; off; off >>= 1) sm += __shfl_xor(sm, off, 64);
      betas16[r][t] = f2h(e * __builtin_amdgcn_rcpf(sm));
    }
    __syncthreads();

    // ---- B2 (grp 0,2): ct[m] = sum_t beta[t]*E[t][m]; + ytil reduce ----
    if (((j >> 8) & 1) == 0) {
      const int r = j >> 9;
      const u16* __restrict__ ep = &e16T[r][n * ES];
      float acc = 0.f;
#pragma unroll
      for (int t0 = 0; t0 < TT; t0 += 8) {
        h2 e0 = *(const h2*)(ep + t0);
        h2 e1 = *(const h2*)(ep + t0 + 2);
        h2 e2 = *(const h2*)(ep + t0 + 4);
        h2 e3 = *(const h2*)(ep + t0 + 6);
        H8 bp = *(const H8*)&betas16[r][t0];
        acc = FDOT2(bp.p[0], e0, acc);
        acc = FDOT2(bp.p[1], e1, acc);
        acc = FDOT2(bp.p[2], e2, acc);
        acc = FDOT2(bp.p[3], e3, acc);
      }
      ((u16*)ctx16p[r])[n] = f2h(acc);
      float p = acc * wt_w[n];
#pragma unroll
      for (int off = 32; off; off >>= 1) p += __shfl_xor(p, off, 64);
      if ((j & 63) == 0) red[wv] = p;   // wv 0..3 (r0), 8..11 (r1)
    }
    __syncthreads();

    // ---- combine partials + gates (grp0, both rows) ----
    if (grp == 0) {
      float yt0 = red[0] + red[1] + red[2] + red[3] + ysh[0][step] * wtM + wtb;
      float yt1 = red[8] + red[9] + red[10] + red[11] + ysh[1][step] * wtM + wtb;
      gates_apply(0, s0 + pg[0][n], s2 + pg[2][n], s4 + pg[4][n],
                  pg3[0][n] + pg3[2][n], yt0);
      gates_apply(1, s1 + pg[1][n], s3 + pg[3][n], s5 + pg[5][n],
                  pg3[1][n] + pg3[3][n], yt1);
    }
    __syncthreads();
  }

  // ================= finals =================
  // ctdot from final f16 ct (same precision path as head)
  if (((j >> 8) & 1) == 0) {
    const int r = j >> 9;
    float p = h2f(((const u16*)ctx16p[r])[n]) * wt_w[n];
#pragma unroll
    for (int off = 32; off; off >>= 1) p += __shfl_xor(p, off, 64);
    if ((j & 63) == 0) red[wv] = p;
  }
  __syncthreads();
  const float ctd0 = red[0] + red[1] + red[2] + red[3];
  const float ctd1 = red[8] + red[9] + red[10] + red[11];

  head_store(0);  // y_Tp1 (sc[] holds it for train==0 feedback)

  const int tr = train[0];
  for (int e = 0; e < 2; ++e) {
    float m0, m1, m2, m3, m4, m5;
    mv4(m0, m1, m2, m3, m4, m5);
    if (grp == 1) {
      pg[0][n] = m0; pg[1][n] = m1; pg[2][n] = m2;
      pg[3][n] = m3; pg[4][n] = m4; pg[5][n] = m5;
    } else if (grp == 2) {
      pg3[0][n] = m0; pg3[1][n] = m1;
    } else if (grp == 3) {
      pg3[2][n] = m0; pg3[3][n] = m1;
    }
    __syncthreads();
    if (grp == 0) {
      float inp0 = tr ? tar[(size_t)b0 * 2 + e] : sc[0];
      float inp1 = tr ? tar[(size_t)(b0 + 1) * 2 + e] : sc[1];
      float yt0 = ctd0 + inp0 * wtM + wtb;
      float yt1 = ctd1 + inp1 * wtM + wtb;
      gates_apply(0, m0 + pg[0][n], m2 + pg[2][n], m4 + pg[4][n],
                  pg3[0][n] + pg3[2][n], yt0);
      gates_apply(1, m1 + pg[1][n], m3 + pg[3][n], m5 + pg[5][n],
                  pg3[1][n] + pg3[3][n], yt1);
    }
    __syncthreads();
    head_store(1 + e);
  }
}

extern "C" void kernel_launch(void* const* d_in, const int* in_sizes, int n_in,
                              void* d_out, int out_size, void* d_ws, size_t ws_size,
                              hipStream_t stream) {
  const float* E     = (const float*)d_in[0];
  const float* yin   = (const float*)d_in[1];
  const float* tar   = (const float*)d_in[2];
  const int*   train = (const int*)d_in[3];
  const float* Wd_w  = (const float*)d_in[4];
  const float* Wd_b  = (const float*)d_in[5];
  const float* Ud_w  = (const float*)d_in[6];
  const float* vd_w  = (const float*)d_in[7];
  const float* wt_w  = (const float*)d_in[8];
  const float* wt_b  = (const float*)d_in[9];
  const float* Wy_w  = (const float*)d_in[10];
  const float* Wy_b  = (const float*)d_in[11];
  const float* vy_w  = (const float*)d_in[12];
  const float* vy_b  = (const float*)d_in[13];
  const float* Wih   = (const float*)d_in[14];
  const float* Whh   = (const float*)d_in[15];
  const float* bih   = (const float*)d_in[16];
  const float* bhh   = (const float*)d_in[17];

  float* out = (float*)d_out;

  if (ws_size >= (size_t)WQ_BYTES) {
    u16* wq = (u16*)d_ws;
    prep_kernel<<<dim3(WQ_ELEMS / 256), dim3(256), 0, stream>>>(
        Wd_w, Whh, Wy_w, wq);
    scan_kernel<1><<<dim3(BB / NROW), dim3(NTH), 0, stream>>>(
        E, yin, tar, train, wq + WD16_OFF, Wd_b, Ud_w, vd_w, wt_w, wt_b,
        wq + WY16_OFF, Wy_b, vy_w, vy_b, Wih, wq + WHH16_OFF, bih, bhh, out);
  } else {
    scan_kernel<0><<<dim3(BB / NROW), dim3(NTH), 0, stream>>>(
        E, yin, tar, train, Wd_w, Wd_b, Ud_w, vd_w, wt_w, wt_b,
        Wy_w, Wy_b, vy_w, vy_b, Wih, Whh, bih, bhh, out);
  }

  (void)in_sizes; (void)n_in; (void)out_size;
}